// Round 2
// baseline (2477.691 us; speedup 1.0000x reference)
//
#include <hip/hip_runtime.h>
#include <math.h>

namespace {
constexpr int Kc = 1024;   // num_embeddings
constexpr int Dd = 64;     // embedding_dim

// numpy pairwise_sum of squares, n=64, exact numpy op order:
//   tmp[d] = fl(a[d]*a[d]) elementwise (rounded BEFORE summing -> contract off)
//   r[j]=tmp[j]; for i=8..56 step 8: r[j]+=tmp[i+j];
//   res = ((r0+r1)+(r2+r3)) + ((r4+r5)+(r6+r7))
__device__ inline float np_sumsq64(const float* __restrict__ a) {
#pragma clang fp contract(off)
    float r[8];
    #pragma unroll
    for (int j = 0; j < 8; ++j) r[j] = a[j] * a[j];
    #pragma unroll
    for (int i = 8; i < 64; i += 8) {
        #pragma unroll
        for (int j = 0; j < 8; ++j) {
            float s = a[i + j] * a[i + j];   // rounded square
            r[j] = r[j] + s;                 // no FMA fusion (contract off)
        }
    }
    return ((r[0] + r[1]) + (r[2] + r[3])) + ((r[4] + r[5]) + (r[6] + r[7]));
}

// ---- precompute ee[k] = np.sum(emb*emb, axis=1) bitwise; also zero hist ----
__global__ void k_ee(const float* __restrict__ emb, float* __restrict__ ee,
                     unsigned int* __restrict__ hist) {
    int k = blockIdx.x * blockDim.x + threadIdx.x;
    ee[k] = np_sumsq64(emb + (size_t)k * Dd);
    hist[k] = 0u;
}

// ---- main: entry-per-lane layout --------------------------------------------
// Block = 256 thr (4 waves), 64 pixels (contiguous hw). Lane holds ONE codebook
// row (64 VGPRs, static idx); wave w covers tiles {w, w+4, w+8, w+12} of 64
// entries each. The wave-uniform FMA operand is x[p][d], contiguous over p ->
// compiler emits one s_load_dwordx16 (scalar pipe, imm offset) per 16 FMAs:
// near-pure VALU issue, no per-thread x array to spill (v2 lesson: VGPR=44
// meant x[64] went to scratch -> 1 GB scratch traffic).
// Per-entry numerics identical to v1: acc sequential fmaf d=0..63, single acc;
// dist = fmaf(-2, g, xx+ee). Argmin exact (dist, idx) lexicographic everywhere
// -> partition/order independent.
__global__ __launch_bounds__(256, 2) void k_main(
    const float* __restrict__ inputs, const float* __restrict__ emb,
    const float* __restrict__ ee_g, float* __restrict__ quant,
    float* __restrict__ enc, float* __restrict__ idx_out,
    unsigned int* __restrict__ hist, float* __restrict__ partials)
{
    __shared__ float swb[4][64];
    __shared__ int   swi[4][64];

    const int tid = threadIdx.x;
    const int w   = tid >> 6;          // wave id (uniform per wave)
    const int l   = tid & 63;
    const int blk = blockIdx.x;
    const int b   = blk >> 4;          // 16 blocks per batch image
    const int hw0 = (blk & 15) << 6;   // first pixel (contiguous 64)

    // per-lane ||x||^2 of pixel l (numpy order); xl is fully consumed here
    float xxv;
    {
        const float* xin = inputs + (size_t)b * 65536 + hw0 + l;
        float xl[64];
        #pragma unroll
        for (int d = 0; d < 64; ++d) xl[d] = xin[d * 1024];
        xxv = np_sumsq64(xl);
    }

    const float* __restrict__ xbase = inputs + (size_t)b * 65536 + hw0; // uniform
    float4* __restrict__ encb = (float4*)enc + (size_t)blk * 16384;

    #pragma unroll 1
    for (int pg = 0; pg < 4; ++pg) {       // 4 groups of 16 pixels
        const int p0 = pg << 4;
        float best[16]; int bidx[16];
        #pragma unroll
        for (int p = 0; p < 16; ++p) { best[p] = INFINITY; bidx[p] = 0x7fffffff; }

        #pragma unroll 1
        for (int t = 0; t < 4; ++t) {
            const int tile = w + (t << 2);             // wave-uniform tile id
            const int kk   = (tile << 6) + l;          // this lane's entry
            // lane's codebook row: 16 x float4 (L2-resident after first touch)
            const float4* __restrict__ er = (const float4*)(emb + ((size_t)kk << 6));
            float4 r4[16];
            #pragma unroll
            for (int i = 0; i < 16; ++i) r4[i] = er[i];
            const float eev = ee_g[kk];

            float acc[16];
            #pragma unroll
            for (int p = 0; p < 16; ++p) acc[p] = 0.f;

            const float* __restrict__ xs = xbase + p0;  // uniform base
            #pragma unroll
            for (int d = 0; d < 64; ++d) {
                const float rv = ((const float*)r4)[d];   // static index -> VGPR
                #pragma unroll
                for (int p = 0; p < 16; ++p)              // 16 contiguous scalars
                    acc[p] = fmaf(xs[d * 1024 + p], rv, acc[p]);
            }

            #pragma unroll
            for (int p = 0; p < 16; ++p) {
                const float xxp = __int_as_float(
                    __builtin_amdgcn_readlane(__float_as_int(xxv), p0 + p));
                const float A    = xxp + eev;             // one rounding (as v1)
                const float dist = fmaf(-2.f, acc[p], A); // one rounding (as v1)
                const bool lt = (dist < best[p]) || (dist == best[p] && kk < bidx[p]);
                best[p] = lt ? dist : best[p];
                bidx[p] = lt ? kk   : bidx[p];
            }

            // enc zero-fill: chunk (pg*4+t) of 1024 float4; pg's 16 rows are
            // fully zeroed by the time pg's tiles are done (one-hot is post-sync)
            {
                float4* e4 = encb + (((pg << 2) + t) << 10) + tid;
                const float4 z{0.f, 0.f, 0.f, 0.f};
                e4[0] = z; e4[256] = z; e4[512] = z; e4[768] = z;
            }
        }

        // wave-wide exact argmin butterfly (all lanes end with wave minimum)
        #pragma unroll
        for (int p = 0; p < 16; ++p) {
            float bd = best[p]; int bi = bidx[p];
            #pragma unroll
            for (int m = 32; m > 0; m >>= 1) {
                const float od = __shfl_xor(bd, m, 64);
                const int   oi = __shfl_xor(bi, m, 64);
                const bool lt = (od < bd) || (od == bd && oi < bi);
                bd = lt ? od : bd; bi = lt ? oi : bi;
            }
            if (l == 0) { swb[w][p0 + p] = bd; swi[w][p0 + p] = bi; }
        }
    }

    __syncthreads();   // all waves' results in LDS; enc zero-fill drained

    if (tid < 64) {    // v1-style coalesced epilogue: pixel = lane
        float bd = swb[0][l]; int bi = swi[0][l];
        #pragma unroll
        for (int q = 1; q < 4; ++q) {
            const float od = swb[q][l]; const int oi = swi[q][l];
            const bool lt = (od < bd) || (od == bd && oi < bi);
            bd = lt ? od : bd; bi = lt ? oi : bi;
        }
        const int n = (blk << 6) + l;

        // quantized output: gather codebook row, store NCHW (coalesced per d)
        {
            const float4* ebq = (const float4*)(emb + ((size_t)bi << 6));
            float* qout = quant + (size_t)b * 65536 + hw0 + l;
            #pragma unroll
            for (int i = 0; i < 16; ++i) {
                const float4 v = ebq[i];
                qout[(i * 4 + 0) * 1024] = v.x;
                qout[(i * 4 + 1) * 1024] = v.y;
                qout[(i * 4 + 2) * 1024] = v.z;
                qout[(i * 4 + 3) * 1024] = v.w;
            }
        }

        idx_out[n] = (float)bi;
        atomicAdd(hist + bi, 1u);
        enc[((size_t)n << 10) + bi] = 1.0f;   // one-hot into zeroed row

        // loss partial: dist_min == ||x - e*||^2
        float v = bd;
        #pragma unroll
        for (int off = 32; off > 0; off >>= 1) v += __shfl_down(v, off, 64);
        if (l == 0) partials[blk] = v;
    }
}

// ---- final: perplexity from histogram, loss from partials (1 sync total) ----
__global__ __launch_bounds__(1024) void k_fin(
    const unsigned int* __restrict__ hist, const float* __restrict__ partials,
    float* __restrict__ loss_out, float* __restrict__ perp_out)
{
    __shared__ double sent[16];
    __shared__ double spar[16];
    const int tid = threadIdx.x;

    double pv = (double)hist[tid] * (1.0 / 65536.0);
    double e = pv * log(pv + 1e-10);
    double s = (double)partials[tid];

    #pragma unroll
    for (int off = 32; off > 0; off >>= 1) {
        e += __shfl_down(e, off, 64);
        s += __shfl_down(s, off, 64);
    }
    if ((tid & 63) == 0) { sent[tid >> 6] = e; spar[tid >> 6] = s; }
    __syncthreads();

    if (tid == 0) {
        double ent = 0.0, sum = 0.0;
        #pragma unroll
        for (int w = 0; w < 16; ++w) { ent += sent[w]; sum += spar[w]; }
        double perp = exp(-ent);
        double mean = sum * (1.0 / 4194304.0);   // sum ||x-e||^2 / (N*D)
        double loss = 1.25 * mean + 0.1 * (1024.0 - perp) / 1024.0;
        loss_out[0] = (float)loss;
        perp_out[0] = (float)perp;
    }
}
} // namespace

extern "C" void kernel_launch(void* const* d_in, const int* in_sizes, int n_in,
                              void* d_out, int out_size, void* d_ws, size_t ws_size,
                              hipStream_t stream)
{
    const float* inputs = (const float*)d_in[0];   // [64,64,32,32] fp32
    const float* emb    = (const float*)d_in[1];   // [1024,64] fp32
    float* out = (float*)d_out;

    float* loss_out = out;                            // [1]
    float* quant    = out + 1;                        // [64,64,32,32]
    float* perp_out = out + 1 + 4194304;              // [1]
    float* enc      = out + 2 + 4194304;              // [65536,1024]
    float* idx_out  = out + 2 + 4194304 + 67108864;   // [65536,1]

    unsigned int* hist = (unsigned int*)d_ws;         // [1024] u32
    float* partials    = (float*)d_ws + 1024;         // [1024] f32 (fully overwritten)
    float* ee          = (float*)d_ws + 2048;         // [1024] f32

    k_ee<<<Kc / 256, 256, 0, stream>>>(emb, ee, hist);
    k_main<<<65536 / 64, 256, 0, stream>>>(inputs, emb, ee, quant, enc, idx_out, hist, partials);
    k_fin<<<1, 1024, 0, stream>>>(hist, partials, loss_out, perp_out);
}

// Round 3
// 751.686 us; speedup vs baseline: 3.2962x; 3.2962x over previous
//
#include <hip/hip_runtime.h>
#include <math.h>

namespace {
constexpr int Kc = 1024;   // num_embeddings
constexpr int Dd = 64;     // embedding_dim

// numpy pairwise_sum of squares, n=64, exact numpy op order:
//   tmp[d] = fl(a[d]*a[d]) elementwise (rounded BEFORE summing -> contract off)
//   r[j]=tmp[j]; for i=8..56 step 8: r[j]+=tmp[i+j];
//   res = ((r0+r1)+(r2+r3)) + ((r4+r5)+(r6+r7))
__device__ inline float np_sumsq64(const float* __restrict__ a) {
#pragma clang fp contract(off)
    float r[8];
    #pragma unroll
    for (int j = 0; j < 8; ++j) r[j] = a[j] * a[j];
    #pragma unroll
    for (int i = 8; i < 64; i += 8) {
        #pragma unroll
        for (int j = 0; j < 8; ++j) {
            float s = a[i + j] * a[i + j];   // rounded square
            r[j] = r[j] + s;                 // no FMA fusion (contract off)
        }
    }
    return ((r[0] + r[1]) + (r[2] + r[3])) + ((r[4] + r[5]) + (r[6] + r[7]));
}

// ---- precompute ee[k] = np.sum(emb*emb, axis=1) bitwise; also zero hist ----
__global__ void k_ee(const float* __restrict__ emb, float* __restrict__ ee,
                     unsigned int* __restrict__ hist) {
    int k = blockIdx.x * blockDim.x + threadIdx.x;
    ee[k] = np_sumsq64(emb + (size_t)k * Dd);
    hist[k] = 0u;
}

// ---- main: v1 register shape (pixel-per-lane, x[64] in VGPRs) + LDS codebook -
// Block = 256 thr (4 waves), 64 pixels; every wave holds the same 64 pixels
// (lane = pixel). Codebook streamed through LDS in 16 chunks of 64 entries
// (16 KB), double-buffered, reg-staged (loads issued before compute, ds_write
// after -> HBM latency hidden under FMAs). Wave w computes entries
// [w*16, w*16+16) of each chunk via uniform-address ds_read broadcasts
// (conflict-free). ILP-2: two independent single-accumulator fmaf chains.
// v2/v3 lesson: no per-lane arrays beyond x[64] -> no spill.
// Numerics identical to v1: per-entry sequential fmaf d=0..63 single acc;
// dist = fmaf(-2, g, xx+ee); exact (dist,idx) tie-break -> order-independent.
__global__ __launch_bounds__(256, 4) void k_main(
    const float* __restrict__ inputs, const float* __restrict__ emb,
    const float* __restrict__ ee_g, float* __restrict__ quant,
    float* __restrict__ enc, float* __restrict__ idx_out,
    unsigned int* __restrict__ hist, float* __restrict__ partials)
{
    __shared__ float s_e[2][64 * 64];   // 2 x 16 KB entry chunks
    __shared__ float s_ee[Kc];          // 4 KB
    __shared__ float swb[4][64];
    __shared__ int   swi[4][64];

    const int tid = threadIdx.x;
    const int w   = tid >> 6;          // wave id
    const int l   = tid & 63;          // pixel within block
    const int blk = blockIdx.x;
    const int b   = blk >> 4;          // 16 blocks per batch image
    const int hw0 = (blk & 15) << 6;   // first pixel (contiguous 64)

    // x[d] = inputs[b, d, hw0+l]  (coalesced 256B per d across the wave)
    const float* xin = inputs + (size_t)b * 65536 + hw0 + l;
    float x[64];
    #pragma unroll
    for (int d = 0; d < 64; ++d) x[d] = xin[d * 1024];
    const float xx = np_sumsq64(x);    // numpy-order fp32 ||x||^2

    // stage ee (1024 floats) and chunk 0 (16 KB) into LDS
    {
        const float4 v = ((const float4*)ee_g)[tid];
        ((float4*)s_ee)[tid] = v;
        const float4* g = (const float4*)emb + tid;   // chunk 0
        float4 v0 = g[0], v1 = g[256], v2 = g[512], v3 = g[768];
        float4* s = (float4*)s_e[0] + tid;
        s[0] = v0; s[256] = v1; s[512] = v2; s[768] = v3;
    }
    __syncthreads();

    float4* __restrict__ encb = (float4*)enc + (size_t)blk * 16384;

    float best = INFINITY;
    int   bidx = 0x7fffffff;

    #pragma unroll 1
    for (int c = 0; c < 16; ++c) {
        const int cur = c & 1;

        // issue next-chunk global loads EARLY (latency hides under FMAs)
        float4 n0, n1, n2, n3;
        if (c < 15) {
            const float4* g = (const float4*)emb + (c + 1) * 1024 + tid;
            n0 = g[0]; n1 = g[256]; n2 = g[512]; n3 = g[768];
        }

        // this wave's 16 entries of chunk c, ILP-2
        const float* __restrict__ Eb = s_e[cur] + (w << 4) * 64;
        const int kbase = (c << 6) + (w << 4);
        #pragma unroll 1
        for (int i = 0; i < 16; i += 2) {
            const float* __restrict__ E0 = Eb + i * 64;
            float g0 = 0.f, g1 = 0.f;
            #pragma unroll
            for (int d = 0; d < 64; ++d) {
                g0 = fmaf(x[d], E0[d],      g0);   // uniform ds_read broadcast
                g1 = fmaf(x[d], E0[64 + d], g1);
            }
            const int k0 = kbase + i;
            const float A0 = xx + s_ee[k0];        // one rounding (as v1)
            const float A1 = xx + s_ee[k0 + 1];
            const float d0 = fmaf(-2.f, g0, A0);   // one rounding (as v1)
            const float d1 = fmaf(-2.f, g1, A1);
            bool lt;
            lt = (d0 < best) || (d0 == best && k0 < bidx);
            best = lt ? d0 : best;  bidx = lt ? k0 : bidx;
            lt = (d1 < best) || (d1 == best && (k0 + 1) < bidx);
            best = lt ? d1 : best;  bidx = lt ? (k0 + 1) : bidx;
        }

        // enc zero-fill: 4 float4 per thread per chunk (256 KB total/block)
        {
            float4* e4 = encb + (c << 10) + tid;
            const float4 z{0.f, 0.f, 0.f, 0.f};
            e4[0] = z; e4[256] = z; e4[512] = z; e4[768] = z;
        }

        // write staged chunk into the other buffer (vmcnt wait lands here,
        // after compute); safe: buffer cur^1 was last read in iter c-1,
        // whose trailing barrier has already passed
        if (c < 15) {
            float4* s = (float4*)s_e[cur ^ 1] + tid;
            s[0] = n0; s[256] = n1; s[512] = n2; s[768] = n3;
        }
        __syncthreads();
    }

    // per-thread best is per-pixel already (lane = pixel); merge the 4 waves
    swb[w][l] = best; swi[w][l] = bidx;
    __syncthreads();   // also drains enc zero-fill stores

    if (tid < 64) {    // coalesced epilogue: pixel = lane
        float bd = swb[0][l]; int bi = swi[0][l];
        #pragma unroll
        for (int q = 1; q < 4; ++q) {
            const float od = swb[q][l]; const int oi = swi[q][l];
            const bool lt = (od < bd) || (od == bd && oi < bi);
            bd = lt ? od : bd; bi = lt ? oi : bi;
        }
        const int n = (blk << 6) + l;

        // quantized output: gather codebook row, store NCHW (coalesced per d)
        {
            const float4* ebq = (const float4*)(emb + ((size_t)bi << 6));
            float* qout = quant + (size_t)b * 65536 + hw0 + l;
            #pragma unroll
            for (int i = 0; i < 16; ++i) {
                const float4 v = ebq[i];
                qout[(i * 4 + 0) * 1024] = v.x;
                qout[(i * 4 + 1) * 1024] = v.y;
                qout[(i * 4 + 2) * 1024] = v.z;
                qout[(i * 4 + 3) * 1024] = v.w;
            }
        }

        idx_out[n] = (float)bi;
        atomicAdd(hist + bi, 1u);
        enc[((size_t)n << 10) + bi] = 1.0f;   // one-hot into zeroed row

        // loss partial: dist_min == ||x - e*||^2
        float v = bd;
        #pragma unroll
        for (int off = 32; off > 0; off >>= 1) v += __shfl_down(v, off, 64);
        if (l == 0) partials[blk] = v;
    }
}

// ---- final: perplexity from histogram, loss from partials (1 sync total) ----
__global__ __launch_bounds__(1024) void k_fin(
    const unsigned int* __restrict__ hist, const float* __restrict__ partials,
    float* __restrict__ loss_out, float* __restrict__ perp_out)
{
    __shared__ double sent[16];
    __shared__ double spar[16];
    const int tid = threadIdx.x;

    double pv = (double)hist[tid] * (1.0 / 65536.0);
    double e = pv * log(pv + 1e-10);
    double s = (double)partials[tid];

    #pragma unroll
    for (int off = 32; off > 0; off >>= 1) {
        e += __shfl_down(e, off, 64);
        s += __shfl_down(s, off, 64);
    }
    if ((tid & 63) == 0) { sent[tid >> 6] = e; spar[tid >> 6] = s; }
    __syncthreads();

    if (tid == 0) {
        double ent = 0.0, sum = 0.0;
        #pragma unroll
        for (int w = 0; w < 16; ++w) { ent += sent[w]; sum += spar[w]; }
        double perp = exp(-ent);
        double mean = sum * (1.0 / 4194304.0);   // sum ||x-e||^2 / (N*D)
        double loss = 1.25 * mean + 0.1 * (1024.0 - perp) / 1024.0;
        loss_out[0] = (float)loss;
        perp_out[0] = (float)perp;
    }
}
} // namespace

extern "C" void kernel_launch(void* const* d_in, const int* in_sizes, int n_in,
                              void* d_out, int out_size, void* d_ws, size_t ws_size,
                              hipStream_t stream)
{
    const float* inputs = (const float*)d_in[0];   // [64,64,32,32] fp32
    const float* emb    = (const float*)d_in[1];   // [1024,64] fp32
    float* out = (float*)d_out;

    float* loss_out = out;                            // [1]
    float* quant    = out + 1;                        // [64,64,32,32]
    float* perp_out = out + 1 + 4194304;              // [1]
    float* enc      = out + 2 + 4194304;              // [65536,1024]
    float* idx_out  = out + 2 + 4194304 + 67108864;   // [65536,1]

    unsigned int* hist = (unsigned int*)d_ws;         // [1024] u32
    float* partials    = (float*)d_ws + 1024;         // [1024] f32 (fully overwritten)
    float* ee          = (float*)d_ws + 2048;         // [1024] f32

    k_ee<<<Kc / 256, 256, 0, stream>>>(emb, ee, hist);
    k_main<<<65536 / 64, 256, 0, stream>>>(inputs, emb, ee, quant, enc, idx_out, hist, partials);
    k_fin<<<1, 1024, 0, stream>>>(hist, partials, loss_out, perp_out);
}